// Round 20
// baseline (531.416 us; speedup 1.0000x reference)
//
#include <hip/hip_runtime.h>

#define Nn 100000
#define Ee 600000
#define Hh 128
#define NP 100096  // padded node rows: multiple of 64
#define NT (NP / 64)  // 1564 tiles

typedef float f32x4 __attribute__((ext_vector_type(4)));
typedef _Float16 f16x8 __attribute__((ext_vector_type(8)));

static __device__ __forceinline__ float sigmoidf_(float x) {
  return 1.0f / (1.0f + __expf(-x));
}
static __device__ __forceinline__ float tanh_fast(float x) {
  return 1.0f - 2.0f / (__expf(2.0f * x) + 1.0f);
}
// LDS fragment layout (ushort idx): [kc][rf:4][g:4][c16:16][j:8], bank-swizzled.
static __device__ __forceinline__ int swz(int u) {
  return u ^ (((u >> 11) & 3) << 4);
}

// Degree count: packed u64 per node, hi32 = total degree, lo32 = col count.
__global__ void count_kernel(const int* __restrict__ ei,
                             unsigned long long* __restrict__ pk) {
  int e = blockIdx.x * 256 + threadIdx.x;
  if (e >= Ee) return;
  int r = ei[e], c = ei[Ee + e];
  atomicAdd(&pk[r], 1ULL << 32);
  atomicAdd(&pk[c], (1ULL << 32) | 1ULL);
}

// block sums of cnt (lo32 of pk), plus dis = rsqrt(deg+1) from hi32
__global__ void scan_partial(const unsigned long long* __restrict__ pk,
                             float* __restrict__ dis, int* __restrict__ bsum) {
  __shared__ int s[256];
  int i = blockIdx.x * 256 + threadIdx.x;
  unsigned long long p = (i < Nn) ? pk[i] : 0ULL;
  s[threadIdx.x] = (int)(unsigned)p;
  if (i < Nn) dis[i] = rsqrtf((float)(unsigned)(p >> 32) + 1.0f);
  __syncthreads();
  for (int off = 128; off > 0; off >>= 1) {
    if (threadIdx.x < off) s[threadIdx.x] += s[threadIdx.x + off];
    __syncthreads();
  }
  if (threadIdx.x == 0) bsum[blockIdx.x] = s[0];
}

__global__ void scan_bsums(const int* __restrict__ bsum, int* __restrict__ bpre, int nb) {
  __shared__ int s[512];
  int t = threadIdx.x;
  s[t] = (t < nb) ? bsum[t] : 0;
  __syncthreads();
  for (int off = 1; off < 512; off <<= 1) {
    int u = (t >= off) ? s[t - off] : 0;
    __syncthreads();
    s[t] += u;
    __syncthreads();
  }
  if (t < nb) bpre[t] = (t == 0) ? 0 : s[t - 1];
}

__global__ void scan_final(const unsigned long long* __restrict__ pk,
                           const int* __restrict__ bpre,
                           int* __restrict__ rowptr, int* __restrict__ cursor) {
  __shared__ int s[256];
  int t = threadIdx.x;
  int i = blockIdx.x * 256 + t;
  int v = (i < Nn) ? (int)(unsigned)pk[i] : 0;
  s[t] = v;
  __syncthreads();
  for (int off = 1; off < 256; off <<= 1) {
    int u = (t >= off) ? s[t - off] : 0;
    __syncthreads();
    s[t] += u;
    __syncthreads();
  }
  int excl = s[t] - v;
  int base = bpre[blockIdx.x];
  if (i < Nn) { rowptr[i] = base + excl; cursor[i] = base + excl; }
  if (i == Nn - 1) rowptr[Nn] = base + excl + v;
}

__global__ void fill_kernel(const int* __restrict__ ei, const float* __restrict__ dis,
                            int* __restrict__ cursor, int* __restrict__ csr_src,
                            float* __restrict__ csr_w) {
  int e = blockIdx.x * 256 + threadIdx.x;
  if (e >= Ee) return;
  int r = ei[e], c = ei[Ee + e];
  int p = atomicAdd(&cursor[c], 1);
  csr_src[p] = r;
  csr_w[p] = dis[r] * dis[c];
}

// Fused: pack GRU weights (blocks 0..47), pack MLP W1 (48..51), h0 (52.., 8 dims/thr).
__global__ void prep_misc(const float* __restrict__ Wih, const float* __restrict__ Whh,
                          _Float16* __restrict__ Bhi, _Float16* __restrict__ Blo,
                          const float* __restrict__ Wm1, _Float16* __restrict__ Bmh,
                          _Float16* __restrict__ Bml,
                          const float* __restrict__ X, const float* __restrict__ W0,
                          const float* __restrict__ b0, _Float16* __restrict__ H0) {
  const int b = blockIdx.x;
  if (b < 48) {
    int t = b * 256 + threadIdx.x;  // < 12288
    int c16 = t & 15;
    int g = (t >> 4) & 3;
    int fid = (t >> 6) % 24;
    int kc = t / (24 * 64);
    int gate = fid >> 3, f = fid & 7;
    int c = f * 16 + c16;
    int wrow = gate * 128 + c;
    size_t base = (size_t)t * 8;
#pragma unroll
    for (int j = 0; j < 8; ++j) {
      int k = kc * 32 + g * 8 + j;
      float v = (k < 128) ? Wih[wrow * 128 + k] : Whh[wrow * 128 + (k - 128)];
      _Float16 hi = (_Float16)v;
      Bhi[base + j] = hi;
      Blo[base + j] = (_Float16)(v - (float)hi);
    }
  } else if (b < 52) {
    int t = (b - 48) * 256 + threadIdx.x;  // < 1024
    int c16 = t & 15;
    int g = (t >> 4) & 3;
    int cf = (t >> 6) & 3;
    int kc = t >> 8;
    int c = cf * 16 + c16;
    size_t base = (size_t)t * 8;
#pragma unroll
    for (int j = 0; j < 8; ++j) {
      int k = kc * 32 + g * 8 + j;
      float v = Wm1[c * 128 + k];
      _Float16 hi = (_Float16)v;
      Bmh[base + j] = hi;
      Bml[base + j] = (_Float16)(v - (float)hi);
    }
  } else {
    int t = (b - 52) * 256 + threadIdx.x;  // < NP*16
    int i = t >> 4, d8 = (t & 15) * 8;
    if (i >= NP) return;
    f16x8 ov;
    if (i < Nn) {
      float x0 = X[i * 3 + 0], x1 = X[i * 3 + 1], x2 = X[i * 3 + 2];
#pragma unroll
      for (int j = 0; j < 8; ++j) {
        int d = d8 + j;
        float v = fmaf(x0, W0[d * 3 + 0],
                       fmaf(x1, W0[d * 3 + 1], fmaf(x2, W0[d * 3 + 2], b0[d])));
        v = v > 0.0f ? v : 0.01f * v;
        ov[j] = (_Float16)v;
      }
    } else {
#pragma unroll
      for (int j = 0; j < 8; ++j) ov[j] = (_Float16)0.0f;
    }
    *(f16x8*)(H0 + (size_t)i * Hh + d8) = ov;
  }
}

// ---- GRU body ----
// A operands are exact fp16 in LDS (SA = aggregate fp16-truncated, SE = own rows);
// weights split fp16 hi+lo -> 2 MFMA passes per gate per kc. 192 MFMA/wave.
#define DO_GATE(GB, ACC)                                                              \
  {                                                                                   \
    size_t boff = (((size_t)(kc * 24 + (GB)*8 + wave) * 4 + g) * 16 + c16) * 8;       \
    f16x8 bH = *(const f16x8*)(Bhi + boff);                                           \
    f16x8 bL = *(const f16x8*)(Blo + boff);                                           \
    _Pragma("unroll") for (int rf = 0; rf < 4; ++rf)                                  \
        ACC[rf] = __builtin_amdgcn_mfma_f32_16x16x32_f16(aE[rf], bH, ACC[rf], 0, 0, 0); \
    _Pragma("unroll") for (int rf = 0; rf < 4; ++rf)                                  \
        ACC[rf] = __builtin_amdgcn_mfma_f32_16x16x32_f16(aE[rf], bL, ACC[rf], 0, 0, 0); \
  }

// Single-barrier GRU body. __VA_ARGS__ = extra prefetch statements executed right
// after the own-row prefetch (used by last2 to pull h1..h3 own chunks early).
#define GRU_BODY(...)                                                                 \
  const int tid = threadIdx.x;                                                        \
  const int tile = blockIdx.x;                                                        \
  const long rowbase = (long)tile * 64;                                               \
  const int local = tid >> 3;                                                         \
  const int sub = tid & 7;                                                            \
  const int eg = sub & 1;                                                             \
  const int dg = sub >> 1;                                                            \
  const int rf0 = local >> 4, c16l = local & 15;                                      \
  const int lwr = dg * 2048 + rf0 * 512 + c16l * 8;                                   \
  const _Float16* ownp = Hp + (size_t)(rowbase + local) * Hh + dg * 32 + eg * 16;     \
  f16x8 own0 = *(const f16x8*)ownp;                                                   \
  f16x8 own1 = *(const f16x8*)(ownp + 8);                                             \
  __VA_ARGS__                                                                         \
  {                                                                                   \
    const long node = rowbase + local;                                                \
    float acc[32];                                                                    \
    _Pragma("unroll") for (int m = 0; m < 32; ++m) acc[m] = 0.0f;                     \
    if (node < Nn) {                                                                  \
      const int eEnd = rowptr[node + 1];                                              \
      int e = rowptr[node] + eg;                                                      \
      const _Float16* hb = Hp + dg * 32;                                              \
      for (; e + 2 < eEnd; e += 4) {                                                  \
        const int s0 = csr_src[e], s1 = csr_src[e + 2];                               \
        const float w0 = csr_w[e], w1 = csr_w[e + 2];                                 \
        const f16x8* p0 = (const f16x8*)(hb + (size_t)s0 * Hh);                       \
        const f16x8* p1 = (const f16x8*)(hb + (size_t)s1 * Hh);                       \
        f16x8 va[4], vb[4];                                                           \
        _Pragma("unroll") for (int q = 0; q < 4; ++q) va[q] = p0[q];                  \
        _Pragma("unroll") for (int q = 0; q < 4; ++q) vb[q] = p1[q];                  \
        _Pragma("unroll") for (int q = 0; q < 4; ++q)                                 \
            _Pragma("unroll") for (int m = 0; m < 8; ++m)                             \
                acc[q * 8 + m] = fmaf(w1, (float)vb[q][m],                            \
                                      fmaf(w0, (float)va[q][m], acc[q * 8 + m]));     \
      }                                                                               \
      if (e < eEnd) {                                                                 \
        const int s0 = csr_src[e];                                                    \
        const float w0 = csr_w[e];                                                    \
        const f16x8* p0 = (const f16x8*)(hb + (size_t)s0 * Hh);                       \
        f16x8 va[4];                                                                  \
        _Pragma("unroll") for (int q = 0; q < 4; ++q) va[q] = p0[q];                  \
        _Pragma("unroll") for (int q = 0; q < 4; ++q)                                 \
            _Pragma("unroll") for (int m = 0; m < 8; ++m)                             \
                acc[q * 8 + m] = fmaf(w0, (float)va[q][m], acc[q * 8 + m]);           \
      }                                                                               \
    }                                                                                 \
    _Pragma("unroll") for (int m = 0; m < 32; ++m) acc[m] += __shfl_xor(acc[m], 1);   \
    if (eg == 0) {                                                                    \
      _Pragma("unroll") for (int g2 = 0; g2 < 4; ++g2) {                              \
        f16x8 vh;                                                                     \
        _Pragma("unroll") for (int j = 0; j < 8; ++j)                                 \
            vh[j] = (_Float16)acc[g2 * 8 + j];                                        \
        *(f16x8*)(SA + swz(lwr + g2 * 128)) = vh;                                     \
      }                                                                               \
    }                                                                                 \
    *(f16x8*)(SE + swz(lwr + (eg * 2 + 0) * 128)) = own0;                             \
    *(f16x8*)(SE + swz(lwr + (eg * 2 + 1) * 128)) = own1;                             \
  }                                                                                   \
  __syncthreads();                                                                    \
  const int wave = tid >> 6, lane = tid & 63;                                         \
  const int g = lane >> 4, c16 = lane & 15;                                           \
  const int lbase = g * 128 + c16 * 8;                                                \
  f32x4 accR[4], accZ[4], accXN[4], accHN[4];                                         \
  _Pragma("unroll") for (int rf = 0; rf < 4; ++rf) {                                  \
    accR[rf] = (f32x4){0.f, 0.f, 0.f, 0.f};                                           \
    accZ[rf] = (f32x4){0.f, 0.f, 0.f, 0.f};                                           \
    accXN[rf] = (f32x4){0.f, 0.f, 0.f, 0.f};                                          \
    accHN[rf] = (f32x4){0.f, 0.f, 0.f, 0.f};                                          \
  }                                                                                   \
  _Pragma("unroll") for (int kc = 0; kc < 4; ++kc) {                                  \
    f16x8 aE[4];                                                                      \
    _Pragma("unroll") for (int rf = 0; rf < 4; ++rf) {                                \
      int off = swz(kc * 2048 + rf * 512 + lbase);                                    \
      aE[rf] = *(const f16x8*)(SA + off);                                             \
    }                                                                                 \
    DO_GATE(0, accR)                                                                  \
    DO_GATE(1, accZ)                                                                  \
    DO_GATE(2, accXN)                                                                 \
  }                                                                                   \
  _Pragma("unroll") for (int kc = 4; kc < 8; ++kc) {                                  \
    f16x8 aE[4];                                                                      \
    _Pragma("unroll") for (int rf = 0; rf < 4; ++rf) {                                \
      int off = swz((kc - 4) * 2048 + rf * 512 + lbase);                              \
      aE[rf] = *(const f16x8*)(SE + off);                                             \
    }                                                                                 \
    DO_GATE(0, accR)                                                                  \
    DO_GATE(1, accZ)                                                                  \
    DO_GATE(2, accHN)                                                                 \
  }                                                                                   \
  const int c = wave * 16 + c16;                                                      \
  const float br = bih[c] + bhh[c];                                                   \
  const float bz = bih[128 + c] + bhh[128 + c];                                       \
  const float bxn = bih[256 + c];                                                     \
  const float bhn = bhh[256 + c];                                                     \
  const int kcs = c >> 5;                                                             \
  const int gs = (c >> 3) & 3;                                                        \
  const int js = c & 7;

// ---- Mid iterations: write Hn. ONE barrier total. LDS 32KB. ----
// __launch_bounds__(512, 4): DO NOT raise to 8 — caps VGPR at 64 and spills the
// accumulator set to scratch (r16: 5x slowdown, 1.9GB scratch traffic/dispatch).
__global__ __launch_bounds__(512, 4) void gcn_gru_fused(
    const _Float16* __restrict__ Hp, _Float16* __restrict__ Hn,
    const int* __restrict__ csr_src, const float* __restrict__ csr_w,
    const int* __restrict__ rowptr,
    const _Float16* __restrict__ Bhi, const _Float16* __restrict__ Blo,
    const float* __restrict__ bih, const float* __restrict__ bhh) {
  __shared__ ushort SA[8192];
  __shared__ ushort SE[8192];
  GRU_BODY()
#pragma unroll
  for (int rf = 0; rf < 4; ++rf) {
#pragma unroll
    for (int reg = 0; reg < 4; ++reg) {
      const int lr = g * 4 + reg;
      const int hoff = swz(kcs * 2048 + rf * 512 + gs * 128 + lr * 8 + js);
      float hold = (float)*(const _Float16*)&SE[hoff];
      float rr = sigmoidf_(accR[rf][reg] + br);
      float zz = sigmoidf_(accZ[rf][reg] + bz);
      float nn = tanh_fast(accXN[rf][reg] + bxn + rr * (accHN[rf][reg] + bhn));
      Hn[(size_t)(rowbase + rf * 16 + lr) * Hh + c] =
          (_Float16)((1.0f - zz) * nn + zz * hold);
    }
  }
}

// ---- Last iteration: h5 -> LDS, fuse max(h1..h5) + MLP, write out. LDS 32KB. ----
// h1..h3 own-row chunks prefetched at kernel top (regs), h4 chunk = own0/own1:
// the max phase does NO global reads; their HBM time overlaps gather+MFMA.
__global__ __launch_bounds__(512, 4) void gcn_gru_last2(
    const _Float16* __restrict__ Hp, const _Float16* __restrict__ Ha,
    const _Float16* __restrict__ Hb, const _Float16* __restrict__ Hc,
    const int* __restrict__ csr_src, const float* __restrict__ csr_w,
    const int* __restrict__ rowptr,
    const _Float16* __restrict__ Bhi, const _Float16* __restrict__ Blo,
    const float* __restrict__ bih, const float* __restrict__ bhh,
    const _Float16* __restrict__ Bmh, const _Float16* __restrict__ Bml,
    const float* __restrict__ bm1, const float* __restrict__ Wm2,
    const float* __restrict__ bm2, float* __restrict__ out) {
  __shared__ ushort S[16384];  // SA | SE; overlaid by hid[64][66] fp32 at the end
  ushort* SA = S;
  ushort* SE = S + 8192;
  f16x8 pa0, pa1, pb0, pb1, pc0, pc1;
  GRU_BODY(
    {
      const size_t oo = (size_t)(ownp - Hp);
      pa0 = *(const f16x8*)(Ha + oo);
      pa1 = *(const f16x8*)(Ha + oo + 8);
      pb0 = *(const f16x8*)(Hb + oo);
      pb1 = *(const f16x8*)(Hb + oo + 8);
      pc0 = *(const f16x8*)(Hc + oo);
      pc1 = *(const f16x8*)(Hc + oo + 8);
    })
  __syncthreads();  // all MFMA reads of SA/SE complete before h5 overwrites SA
  // h5 -> SA (fp16, fragment layout); hold from SE (still intact)
#pragma unroll
  for (int rf = 0; rf < 4; ++rf) {
#pragma unroll
    for (int reg = 0; reg < 4; ++reg) {
      const int lr = g * 4 + reg;
      const int hoff = swz(kcs * 2048 + rf * 512 + gs * 128 + lr * 8 + js);
      float hold = (float)*(const _Float16*)&SE[hoff];
      float rr = sigmoidf_(accR[rf][reg] + br);
      float zz = sigmoidf_(accZ[rf][reg] + bz);
      float nn = tanh_fast(accXN[rf][reg] + bxn + rr * (accHN[rf][reg] + bhn));
      *(_Float16*)&SA[hoff] = (_Float16)((1.0f - zz) * nn + zz * hold);
    }
  }
  __syncthreads();

  // max(h5, h1..h4): all operands in registers except h5 (SA); in place in SA
  {
#pragma unroll
    for (int h2 = 0; h2 < 2; ++h2) {
      const int slot = swz(lwr + (eg * 2 + h2) * 128);
      f16x8 m = *(const f16x8*)(SA + slot);
      f16x8 v;
      v = (h2 == 0) ? own0 : own1;  // h4
#pragma unroll
      for (int mm = 0; mm < 8; ++mm) m[mm] = m[mm] > v[mm] ? m[mm] : v[mm];
      v = (h2 == 0) ? pa0 : pa1;  // h1
#pragma unroll
      for (int mm = 0; mm < 8; ++mm) m[mm] = m[mm] > v[mm] ? m[mm] : v[mm];
      v = (h2 == 0) ? pb0 : pb1;  // h2
#pragma unroll
      for (int mm = 0; mm < 8; ++mm) m[mm] = m[mm] > v[mm] ? m[mm] : v[mm];
      v = (h2 == 0) ? pc0 : pc1;  // h3
#pragma unroll
      for (int mm = 0; mm < 8; ++mm) m[mm] = m[mm] > v[mm] ? m[mm] : v[mm];
      *(f16x8*)(SA + slot) = m;
    }
  }
  __syncthreads();

  // MLP MFMA: wave -> (cf = wave>>1, kh = wave&1); A = max (exact fp16) from SA
  const int cf = wave >> 1, kh = wave & 1;
  f32x4 macc[4];
#pragma unroll
  for (int rf = 0; rf < 4; ++rf) macc[rf] = (f32x4){0.f, 0.f, 0.f, 0.f};
#pragma unroll
  for (int q = 0; q < 2; ++q) {
    const int kc = kh * 2 + q;
    f16x8 aE[4];
#pragma unroll
    for (int rf = 0; rf < 4; ++rf) {
      int off = swz(kc * 2048 + rf * 512 + lbase);
      aE[rf] = *(const f16x8*)(SA + off);
    }
    size_t boff = (((size_t)(kc * 4 + cf) * 4 + g) * 16 + c16) * 8;
    f16x8 bH = *(const f16x8*)(Bmh + boff);
    f16x8 bL = *(const f16x8*)(Bml + boff);
#pragma unroll
    for (int rf = 0; rf < 4; ++rf)
      macc[rf] = __builtin_amdgcn_mfma_f32_16x16x32_f16(aE[rf], bH, macc[rf], 0, 0, 0);
#pragma unroll
    for (int rf = 0; rf < 4; ++rf)
      macc[rf] = __builtin_amdgcn_mfma_f32_16x16x32_f16(aE[rf], bL, macc[rf], 0, 0, 0);
  }
  __syncthreads();  // all SA reads done; S is now dead -> overlay hid

  float* hid = (float*)S;  // hid[row][hc] with stride 66 (16.9KB of 32KB)
  const int hc = cf * 16 + c16;
  // kh=0 writes, then kh=1 accumulates (deterministic 2-step combine)
  if (kh == 0) {
#pragma unroll
    for (int rf = 0; rf < 4; ++rf)
#pragma unroll
      for (int reg = 0; reg < 4; ++reg)
        hid[(rf * 16 + g * 4 + reg) * 66 + hc] = macc[rf][reg];
  }
  __syncthreads();
  if (kh == 1) {
#pragma unroll
    for (int rf = 0; rf < 4; ++rf)
#pragma unroll
      for (int reg = 0; reg < 4; ++reg)
        hid[(rf * 16 + g * 4 + reg) * 66 + hc] += macc[rf][reg];
  }
  __syncthreads();

  // Final: 512 threads; thread -> (row = tid>>3, 8 cols), 3 shfl rounds.
  {
    const int row = tid >> 3;
    const int s8 = tid & 7;
    float s = 0.f;
#pragma unroll
    for (int j = 0; j < 8; ++j) {
      const int cc = s8 * 8 + j;
      float v = hid[row * 66 + cc] + bm1[cc];
      v = v > 0.f ? v : 0.01f * v;
      s = fmaf(v, Wm2[cc], s);
    }
    s += __shfl_xor(s, 1);
    s += __shfl_xor(s, 2);
    s += __shfl_xor(s, 4);
    if (s8 == 0) {
      long grow = rowbase + row;
      if (grow < Nn) out[grow] = s + bm2[0];
    }
  }
}

extern "C" void kernel_launch(void* const* d_in, const int* in_sizes, int n_in,
                              void* d_out, int out_size, void* d_ws, size_t ws_size,
                              hipStream_t stream) {
  const float* X = (const float*)d_in[0];
  const int* ei = (const int*)d_in[1];
  const float* W0 = (const float*)d_in[2];
  const float* b0 = (const float*)d_in[3];
  const float* Wih = (const float*)d_in[4];
  const float* Whh = (const float*)d_in[5];
  const float* bih = (const float*)d_in[6];
  const float* bhh = (const float*)d_in[7];
  const float* Wm1 = (const float*)d_in[8];
  const float* bm1 = (const float*)d_in[9];
  const float* Wm2 = (const float*)d_in[10];
  const float* bm2 = (const float*)d_in[11];
  float* out = (float*)d_out;

  char* ws = (char*)d_ws;
  size_t off = 0;
  auto alloc = [&](size_t bytes) -> void* {
    void* p = ws + off;
    off = (off + bytes + 255) & ~(size_t)255;
    return p;
  };
  _Float16* Hs[5];
  for (int i = 0; i < 5; ++i) Hs[i] = (_Float16*)alloc((size_t)NP * Hh * 2);
  _Float16* Bhi = (_Float16*)alloc((size_t)8 * 24 * 4 * 16 * 8 * 2);
  _Float16* Blo = (_Float16*)alloc((size_t)8 * 24 * 4 * 16 * 8 * 2);
  _Float16* Bmh = (_Float16*)alloc((size_t)1024 * 8 * 2);
  _Float16* Bml = (_Float16*)alloc((size_t)1024 * 8 * 2);
  float* dis = (float*)alloc((size_t)Nn * 4);
  unsigned long long* pk = (unsigned long long*)alloc((size_t)Nn * 8);
  int* rowptr = (int*)alloc((size_t)(Nn + 1) * 4);
  int* cursor = (int*)alloc((size_t)Nn * 4);
  int* bsum = (int*)alloc(512 * 4);
  int* bpre = (int*)alloc(512 * 4);
  int* csr_src = (int*)alloc((size_t)Ee * 4);
  float* csr_w = (float*)alloc((size_t)Ee * 4);
  (void)ws_size;
  (void)in_sizes;
  (void)n_in;
  (void)out_size;

  const int NB = (Nn + 255) / 256;  // 391
  const int EB = (Ee + 255) / 256;  // 2344

  hipMemsetAsync(pk, 0, (size_t)Nn * 8, stream);
  count_kernel<<<EB, 256, 0, stream>>>(ei, pk);
  scan_partial<<<NB, 256, 0, stream>>>(pk, dis, bsum);
  scan_bsums<<<1, 512, 0, stream>>>(bsum, bpre, NB);
  scan_final<<<NB, 256, 0, stream>>>(pk, bpre, rowptr, cursor);
  fill_kernel<<<EB, 256, 0, stream>>>(ei, dis, cursor, csr_src, csr_w);
  prep_misc<<<52 + (NP * 16) / 256, 256, 0, stream>>>(Wih, Whh, Bhi, Blo, Wm1, Bmh,
                                                      Bml, X, W0, b0, Hs[0]);

  for (int t = 1; t <= 4; ++t) {
    gcn_gru_fused<<<NT, 512, 0, stream>>>(Hs[t - 1], Hs[t], csr_src, csr_w,
                                          rowptr, Bhi, Blo, bih, bhh);
  }
  gcn_gru_last2<<<NT, 512, 0, stream>>>(Hs[4], Hs[1], Hs[2], Hs[3], csr_src, csr_w,
                                        rowptr, Bhi, Blo, bih, bhh, Bmh, Bml,
                                        bm1, Wm2, bm2, out);
}

// Round 21
// 510.372 us; speedup vs baseline: 1.0412x; 1.0412x over previous
//
#include <hip/hip_runtime.h>

#define Nn 100000
#define Ee 600000
#define Hh 128
#define NP 100096  // padded node rows: multiple of 64
#define NT (NP / 64)  // 1564 tiles

typedef float f32x4 __attribute__((ext_vector_type(4)));
typedef _Float16 f16x8 __attribute__((ext_vector_type(8)));

static __device__ __forceinline__ float sigmoidf_(float x) {
  return 1.0f / (1.0f + __expf(-x));
}
static __device__ __forceinline__ float tanh_fast(float x) {
  return 1.0f - 2.0f / (__expf(2.0f * x) + 1.0f);
}
// LDS fragment layout (ushort idx): [kc][rf:4][g:4][c16:16][j:8], bank-swizzled.
static __device__ __forceinline__ int swz(int u) {
  return u ^ (((u >> 11) & 3) << 4);
}

// Degree count: packed u64 per node, hi32 = total degree, lo32 = col count.
__global__ void count_kernel(const int* __restrict__ ei,
                             unsigned long long* __restrict__ pk) {
  int e = blockIdx.x * 256 + threadIdx.x;
  if (e >= Ee) return;
  int r = ei[e], c = ei[Ee + e];
  atomicAdd(&pk[r], 1ULL << 32);
  atomicAdd(&pk[c], (1ULL << 32) | 1ULL);
}

// block sums of cnt (lo32 of pk), plus dis = rsqrt(deg+1) from hi32
__global__ void scan_partial(const unsigned long long* __restrict__ pk,
                             float* __restrict__ dis, int* __restrict__ bsum) {
  __shared__ int s[256];
  int i = blockIdx.x * 256 + threadIdx.x;
  unsigned long long p = (i < Nn) ? pk[i] : 0ULL;
  s[threadIdx.x] = (int)(unsigned)p;
  if (i < Nn) dis[i] = rsqrtf((float)(unsigned)(p >> 32) + 1.0f);
  __syncthreads();
  for (int off = 128; off > 0; off >>= 1) {
    if (threadIdx.x < off) s[threadIdx.x] += s[threadIdx.x + off];
    __syncthreads();
  }
  if (threadIdx.x == 0) bsum[blockIdx.x] = s[0];
}

__global__ void scan_bsums(const int* __restrict__ bsum, int* __restrict__ bpre, int nb) {
  __shared__ int s[512];
  int t = threadIdx.x;
  s[t] = (t < nb) ? bsum[t] : 0;
  __syncthreads();
  for (int off = 1; off < 512; off <<= 1) {
    int u = (t >= off) ? s[t - off] : 0;
    __syncthreads();
    s[t] += u;
    __syncthreads();
  }
  if (t < nb) bpre[t] = (t == 0) ? 0 : s[t - 1];
}

__global__ void scan_final(const unsigned long long* __restrict__ pk,
                           const int* __restrict__ bpre,
                           int* __restrict__ rowptr, int* __restrict__ cursor) {
  __shared__ int s[256];
  int t = threadIdx.x;
  int i = blockIdx.x * 256 + t;
  int v = (i < Nn) ? (int)(unsigned)pk[i] : 0;
  s[t] = v;
  __syncthreads();
  for (int off = 1; off < 256; off <<= 1) {
    int u = (t >= off) ? s[t - off] : 0;
    __syncthreads();
    s[t] += u;
    __syncthreads();
  }
  int excl = s[t] - v;
  int base = bpre[blockIdx.x];
  if (i < Nn) { rowptr[i] = base + excl; cursor[i] = base + excl; }
  if (i == Nn - 1) rowptr[Nn] = base + excl + v;
}

__global__ void fill_kernel(const int* __restrict__ ei, const float* __restrict__ dis,
                            int* __restrict__ cursor, int* __restrict__ csr_src,
                            float* __restrict__ csr_w) {
  int e = blockIdx.x * 256 + threadIdx.x;
  if (e >= Ee) return;
  int r = ei[e], c = ei[Ee + e];
  int p = atomicAdd(&cursor[c], 1);
  csr_src[p] = r;
  csr_w[p] = dis[r] * dis[c];
}

// Fused: pack GRU weights (blocks 0..47), pack MLP W1 (48..51), h0 (52.., 8 dims/thr).
__global__ void prep_misc(const float* __restrict__ Wih, const float* __restrict__ Whh,
                          _Float16* __restrict__ Bhi, _Float16* __restrict__ Blo,
                          const float* __restrict__ Wm1, _Float16* __restrict__ Bmh,
                          _Float16* __restrict__ Bml,
                          const float* __restrict__ X, const float* __restrict__ W0,
                          const float* __restrict__ b0, _Float16* __restrict__ H0) {
  const int b = blockIdx.x;
  if (b < 48) {
    int t = b * 256 + threadIdx.x;  // < 12288
    int c16 = t & 15;
    int g = (t >> 4) & 3;
    int fid = (t >> 6) % 24;
    int kc = t / (24 * 64);
    int gate = fid >> 3, f = fid & 7;
    int c = f * 16 + c16;
    int wrow = gate * 128 + c;
    size_t base = (size_t)t * 8;
#pragma unroll
    for (int j = 0; j < 8; ++j) {
      int k = kc * 32 + g * 8 + j;
      float v = (k < 128) ? Wih[wrow * 128 + k] : Whh[wrow * 128 + (k - 128)];
      _Float16 hi = (_Float16)v;
      Bhi[base + j] = hi;
      Blo[base + j] = (_Float16)(v - (float)hi);
    }
  } else if (b < 52) {
    int t = (b - 48) * 256 + threadIdx.x;  // < 1024
    int c16 = t & 15;
    int g = (t >> 4) & 3;
    int cf = (t >> 6) & 3;
    int kc = t >> 8;
    int c = cf * 16 + c16;
    size_t base = (size_t)t * 8;
#pragma unroll
    for (int j = 0; j < 8; ++j) {
      int k = kc * 32 + g * 8 + j;
      float v = Wm1[c * 128 + k];
      _Float16 hi = (_Float16)v;
      Bmh[base + j] = hi;
      Bml[base + j] = (_Float16)(v - (float)hi);
    }
  } else {
    int t = (b - 52) * 256 + threadIdx.x;  // < NP*16
    int i = t >> 4, d8 = (t & 15) * 8;
    if (i >= NP) return;
    f16x8 ov;
    if (i < Nn) {
      float x0 = X[i * 3 + 0], x1 = X[i * 3 + 1], x2 = X[i * 3 + 2];
#pragma unroll
      for (int j = 0; j < 8; ++j) {
        int d = d8 + j;
        float v = fmaf(x0, W0[d * 3 + 0],
                       fmaf(x1, W0[d * 3 + 1], fmaf(x2, W0[d * 3 + 2], b0[d])));
        v = v > 0.0f ? v : 0.01f * v;
        ov[j] = (_Float16)v;
      }
    } else {
#pragma unroll
      for (int j = 0; j < 8; ++j) ov[j] = (_Float16)0.0f;
    }
    *(f16x8*)(H0 + (size_t)i * Hh + d8) = ov;
  }
}

// ---- GRU body ----
// A operands are exact fp16 in LDS (SA = aggregate fp16-truncated, SE = own rows);
// weights split fp16 hi+lo -> 2 MFMA passes per gate per kc. 192 MFMA/wave.
#define DO_GATE(GB, ACC)                                                              \
  {                                                                                   \
    size_t boff = (((size_t)(kc * 24 + (GB)*8 + wave) * 4 + g) * 16 + c16) * 8;       \
    f16x8 bH = *(const f16x8*)(Bhi + boff);                                           \
    f16x8 bL = *(const f16x8*)(Blo + boff);                                           \
    _Pragma("unroll") for (int rf = 0; rf < 4; ++rf)                                  \
        ACC[rf] = __builtin_amdgcn_mfma_f32_16x16x32_f16(aE[rf], bH, ACC[rf], 0, 0, 0); \
    _Pragma("unroll") for (int rf = 0; rf < 4; ++rf)                                  \
        ACC[rf] = __builtin_amdgcn_mfma_f32_16x16x32_f16(aE[rf], bL, ACC[rf], 0, 0, 0); \
  }

// Single-barrier GRU body. NOTE (r20 post-mortem): do NOT keep extra registers
// (prefetches) live across the MFMA section — it spills to scratch (66MB WRITE,
// +23% time). own0/own1 die at the SE store.
#define GRU_BODY                                                                      \
  const int tid = threadIdx.x;                                                        \
  const int tile = blockIdx.x;                                                        \
  const long rowbase = (long)tile * 64;                                               \
  const int local = tid >> 3;                                                         \
  const int sub = tid & 7;                                                            \
  const int eg = sub & 1;                                                             \
  const int dg = sub >> 1;                                                            \
  const int rf0 = local >> 4, c16l = local & 15;                                      \
  const int lwr = dg * 2048 + rf0 * 512 + c16l * 8;                                   \
  {                                                                                   \
    const _Float16* ownp = Hp + (size_t)(rowbase + local) * Hh + dg * 32 + eg * 16;   \
    f16x8 own0 = *(const f16x8*)ownp;                                                 \
    f16x8 own1 = *(const f16x8*)(ownp + 8);                                           \
    const long node = rowbase + local;                                                \
    float acc[32];                                                                    \
    _Pragma("unroll") for (int m = 0; m < 32; ++m) acc[m] = 0.0f;                     \
    if (node < Nn) {                                                                  \
      const int eEnd = rowptr[node + 1];                                              \
      int e = rowptr[node] + eg;                                                      \
      const _Float16* hb = Hp + dg * 32;                                              \
      for (; e + 2 < eEnd; e += 4) {                                                  \
        const int s0 = csr_src[e], s1 = csr_src[e + 2];                               \
        const float w0 = csr_w[e], w1 = csr_w[e + 2];                                 \
        const f16x8* p0 = (const f16x8*)(hb + (size_t)s0 * Hh);                       \
        const f16x8* p1 = (const f16x8*)(hb + (size_t)s1 * Hh);                       \
        f16x8 va[4], vb[4];                                                           \
        _Pragma("unroll") for (int q = 0; q < 4; ++q) va[q] = p0[q];                  \
        _Pragma("unroll") for (int q = 0; q < 4; ++q) vb[q] = p1[q];                  \
        _Pragma("unroll") for (int q = 0; q < 4; ++q)                                 \
            _Pragma("unroll") for (int m = 0; m < 8; ++m)                             \
                acc[q * 8 + m] = fmaf(w1, (float)vb[q][m],                            \
                                      fmaf(w0, (float)va[q][m], acc[q * 8 + m]));     \
      }                                                                               \
      if (e < eEnd) {                                                                 \
        const int s0 = csr_src[e];                                                    \
        const float w0 = csr_w[e];                                                    \
        const f16x8* p0 = (const f16x8*)(hb + (size_t)s0 * Hh);                       \
        f16x8 va[4];                                                                  \
        _Pragma("unroll") for (int q = 0; q < 4; ++q) va[q] = p0[q];                  \
        _Pragma("unroll") for (int q = 0; q < 4; ++q)                                 \
            _Pragma("unroll") for (int m = 0; m < 8; ++m)                             \
                acc[q * 8 + m] = fmaf(w0, (float)va[q][m], acc[q * 8 + m]);           \
      }                                                                               \
    }                                                                                 \
    _Pragma("unroll") for (int m = 0; m < 32; ++m) acc[m] += __shfl_xor(acc[m], 1);   \
    if (eg == 0) {                                                                    \
      _Pragma("unroll") for (int g2 = 0; g2 < 4; ++g2) {                              \
        f16x8 vh;                                                                     \
        _Pragma("unroll") for (int j = 0; j < 8; ++j)                                 \
            vh[j] = (_Float16)acc[g2 * 8 + j];                                        \
        *(f16x8*)(SA + swz(lwr + g2 * 128)) = vh;                                     \
      }                                                                               \
    }                                                                                 \
    *(f16x8*)(SE + swz(lwr + (eg * 2 + 0) * 128)) = own0;                             \
    *(f16x8*)(SE + swz(lwr + (eg * 2 + 1) * 128)) = own1;                             \
  }                                                                                   \
  __syncthreads();                                                                    \
  const int wave = tid >> 6, lane = tid & 63;                                         \
  const int g = lane >> 4, c16 = lane & 15;                                           \
  const int lbase = g * 128 + c16 * 8;                                                \
  f32x4 accR[4], accZ[4], accXN[4], accHN[4];                                         \
  _Pragma("unroll") for (int rf = 0; rf < 4; ++rf) {                                  \
    accR[rf] = (f32x4){0.f, 0.f, 0.f, 0.f};                                           \
    accZ[rf] = (f32x4){0.f, 0.f, 0.f, 0.f};                                           \
    accXN[rf] = (f32x4){0.f, 0.f, 0.f, 0.f};                                          \
    accHN[rf] = (f32x4){0.f, 0.f, 0.f, 0.f};                                          \
  }                                                                                   \
  _Pragma("unroll") for (int kc = 0; kc < 4; ++kc) {                                  \
    f16x8 aE[4];                                                                      \
    _Pragma("unroll") for (int rf = 0; rf < 4; ++rf) {                                \
      int off = swz(kc * 2048 + rf * 512 + lbase);                                    \
      aE[rf] = *(const f16x8*)(SA + off);                                             \
    }                                                                                 \
    DO_GATE(0, accR)                                                                  \
    DO_GATE(1, accZ)                                                                  \
    DO_GATE(2, accXN)                                                                 \
  }                                                                                   \
  _Pragma("unroll") for (int kc = 4; kc < 8; ++kc) {                                  \
    f16x8 aE[4];                                                                      \
    _Pragma("unroll") for (int rf = 0; rf < 4; ++rf) {                                \
      int off = swz((kc - 4) * 2048 + rf * 512 + lbase);                              \
      aE[rf] = *(const f16x8*)(SE + off);                                             \
    }                                                                                 \
    DO_GATE(0, accR)                                                                  \
    DO_GATE(1, accZ)                                                                  \
    DO_GATE(2, accHN)                                                                 \
  }                                                                                   \
  const int c = wave * 16 + c16;                                                      \
  const float br = bih[c] + bhh[c];                                                   \
  const float bz = bih[128 + c] + bhh[128 + c];                                       \
  const float bxn = bih[256 + c];                                                     \
  const float bhn = bhh[256 + c];                                                     \
  const int kcs = c >> 5;                                                             \
  const int gs = (c >> 3) & 3;                                                        \
  const int js = c & 7;

// ---- Mid iterations: write Hn. ONE barrier total. LDS 32KB. ----
// __launch_bounds__(512, 4): DO NOT raise to 8 — caps VGPR at 64 and spills the
// accumulator set to scratch (r16: 5x slowdown, 1.9GB scratch traffic/dispatch).
__global__ __launch_bounds__(512, 4) void gcn_gru_fused(
    const _Float16* __restrict__ Hp, _Float16* __restrict__ Hn,
    const int* __restrict__ csr_src, const float* __restrict__ csr_w,
    const int* __restrict__ rowptr,
    const _Float16* __restrict__ Bhi, const _Float16* __restrict__ Blo,
    const float* __restrict__ bih, const float* __restrict__ bhh) {
  __shared__ ushort SA[8192];
  __shared__ ushort SE[8192];
  GRU_BODY
#pragma unroll
  for (int rf = 0; rf < 4; ++rf) {
#pragma unroll
    for (int reg = 0; reg < 4; ++reg) {
      const int lr = g * 4 + reg;
      const int hoff = swz(kcs * 2048 + rf * 512 + gs * 128 + lr * 8 + js);
      float hold = (float)*(const _Float16*)&SE[hoff];
      float rr = sigmoidf_(accR[rf][reg] + br);
      float zz = sigmoidf_(accZ[rf][reg] + bz);
      float nn = tanh_fast(accXN[rf][reg] + bxn + rr * (accHN[rf][reg] + bhn));
      Hn[(size_t)(rowbase + rf * 16 + lr) * Hh + c] =
          (_Float16)((1.0f - zz) * nn + zz * hold);
    }
  }
}

// ---- Last iteration: h5 -> LDS, fuse max(h1..h5) + MLP, write out. LDS 32KB. ----
__global__ __launch_bounds__(512, 4) void gcn_gru_last2(
    const _Float16* __restrict__ Hp, const _Float16* __restrict__ Ha,
    const _Float16* __restrict__ Hb, const _Float16* __restrict__ Hc,
    const int* __restrict__ csr_src, const float* __restrict__ csr_w,
    const int* __restrict__ rowptr,
    const _Float16* __restrict__ Bhi, const _Float16* __restrict__ Blo,
    const float* __restrict__ bih, const float* __restrict__ bhh,
    const _Float16* __restrict__ Bmh, const _Float16* __restrict__ Bml,
    const float* __restrict__ bm1, const float* __restrict__ Wm2,
    const float* __restrict__ bm2, float* __restrict__ out) {
  __shared__ ushort S[16384];  // SA | SE; overlaid by hid[64][66] fp32 at the end
  ushort* SA = S;
  ushort* SE = S + 8192;
  GRU_BODY
  __syncthreads();  // all MFMA reads of SA/SE complete before h5 overwrites SA
  // h5 -> SA (fp16, fragment layout); hold from SE (still intact)
#pragma unroll
  for (int rf = 0; rf < 4; ++rf) {
#pragma unroll
    for (int reg = 0; reg < 4; ++reg) {
      const int lr = g * 4 + reg;
      const int hoff = swz(kcs * 2048 + rf * 512 + gs * 128 + lr * 8 + js);
      float hold = (float)*(const _Float16*)&SE[hoff];
      float rr = sigmoidf_(accR[rf][reg] + br);
      float zz = sigmoidf_(accZ[rf][reg] + bz);
      float nn = tanh_fast(accXN[rf][reg] + bxn + rr * (accHN[rf][reg] + bhn));
      *(_Float16*)&SA[hoff] = (_Float16)((1.0f - zz) * nn + zz * hold);
    }
  }
  __syncthreads();

  // max(h5, h1..h4): each thread its own 2 staging slots (16 dims), in place in SA
  {
    const size_t o = (size_t)(rowbase + local) * Hh + dg * 32 + eg * 16;
#pragma unroll
    for (int h2 = 0; h2 < 2; ++h2) {
      const int slot = swz(lwr + (eg * 2 + h2) * 128);
      f16x8 m = *(const f16x8*)(SA + slot);
      f16x8 v;
      v = *(const f16x8*)(Hp + o + h2 * 8);
#pragma unroll
      for (int mm = 0; mm < 8; ++mm) m[mm] = m[mm] > v[mm] ? m[mm] : v[mm];
      v = *(const f16x8*)(Ha + o + h2 * 8);
#pragma unroll
      for (int mm = 0; mm < 8; ++mm) m[mm] = m[mm] > v[mm] ? m[mm] : v[mm];
      v = *(const f16x8*)(Hb + o + h2 * 8);
#pragma unroll
      for (int mm = 0; mm < 8; ++mm) m[mm] = m[mm] > v[mm] ? m[mm] : v[mm];
      v = *(const f16x8*)(Hc + o + h2 * 8);
#pragma unroll
      for (int mm = 0; mm < 8; ++mm) m[mm] = m[mm] > v[mm] ? m[mm] : v[mm];
      *(f16x8*)(SA + slot) = m;
    }
  }
  __syncthreads();

  // MLP MFMA: wave -> (cf = wave>>1, kh = wave&1); A = max (exact fp16) from SA
  const int cf = wave >> 1, kh = wave & 1;
  f32x4 macc[4];
#pragma unroll
  for (int rf = 0; rf < 4; ++rf) macc[rf] = (f32x4){0.f, 0.f, 0.f, 0.f};
#pragma unroll
  for (int q = 0; q < 2; ++q) {
    const int kc = kh * 2 + q;
    f16x8 aE[4];
#pragma unroll
    for (int rf = 0; rf < 4; ++rf) {
      int off = swz(kc * 2048 + rf * 512 + lbase);
      aE[rf] = *(const f16x8*)(SA + off);
    }
    size_t boff = (((size_t)(kc * 4 + cf) * 4 + g) * 16 + c16) * 8;
    f16x8 bH = *(const f16x8*)(Bmh + boff);
    f16x8 bL = *(const f16x8*)(Bml + boff);
#pragma unroll
    for (int rf = 0; rf < 4; ++rf)
      macc[rf] = __builtin_amdgcn_mfma_f32_16x16x32_f16(aE[rf], bH, macc[rf], 0, 0, 0);
#pragma unroll
    for (int rf = 0; rf < 4; ++rf)
      macc[rf] = __builtin_amdgcn_mfma_f32_16x16x32_f16(aE[rf], bL, macc[rf], 0, 0, 0);
  }
  __syncthreads();  // all SA reads done; S is now dead -> overlay hid

  float* hid = (float*)S;  // hid[row][hc] with stride 66 (16.9KB of 32KB)
  const int hc = cf * 16 + c16;
  // kh=0 writes, then kh=1 accumulates (deterministic 2-step combine)
  if (kh == 0) {
#pragma unroll
    for (int rf = 0; rf < 4; ++rf)
#pragma unroll
      for (int reg = 0; reg < 4; ++reg)
        hid[(rf * 16 + g * 4 + reg) * 66 + hc] = macc[rf][reg];
  }
  __syncthreads();
  if (kh == 1) {
#pragma unroll
    for (int rf = 0; rf < 4; ++rf)
#pragma unroll
      for (int reg = 0; reg < 4; ++reg)
        hid[(rf * 16 + g * 4 + reg) * 66 + hc] += macc[rf][reg];
  }
  __syncthreads();

  // Final: 512 threads; thread -> (row = tid>>3, 8 cols), 3 shfl rounds.
  {
    const int row = tid >> 3;
    const int s8 = tid & 7;
    float s = 0.f;
#pragma unroll
    for (int j = 0; j < 8; ++j) {
      const int cc = s8 * 8 + j;
      float v = hid[row * 66 + cc] + bm1[cc];
      v = v > 0.f ? v : 0.01f * v;
      s = fmaf(v, Wm2[cc], s);
    }
    s += __shfl_xor(s, 1);
    s += __shfl_xor(s, 2);
    s += __shfl_xor(s, 4);
    if (s8 == 0) {
      long grow = rowbase + row;
      if (grow < Nn) out[grow] = s + bm2[0];
    }
  }
}

extern "C" void kernel_launch(void* const* d_in, const int* in_sizes, int n_in,
                              void* d_out, int out_size, void* d_ws, size_t ws_size,
                              hipStream_t stream) {
  const float* X = (const float*)d_in[0];
  const int* ei = (const int*)d_in[1];
  const float* W0 = (const float*)d_in[2];
  const float* b0 = (const float*)d_in[3];
  const float* Wih = (const float*)d_in[4];
  const float* Whh = (const float*)d_in[5];
  const float* bih = (const float*)d_in[6];
  const float* bhh = (const float*)d_in[7];
  const float* Wm1 = (const float*)d_in[8];
  const float* bm1 = (const float*)d_in[9];
  const float* Wm2 = (const float*)d_in[10];
  const float* bm2 = (const float*)d_in[11];
  float* out = (float*)d_out;

  char* ws = (char*)d_ws;
  size_t off = 0;
  auto alloc = [&](size_t bytes) -> void* {
    void* p = ws + off;
    off = (off + bytes + 255) & ~(size_t)255;
    return p;
  };
  _Float16* Hs[5];
  for (int i = 0; i < 5; ++i) Hs[i] = (_Float16*)alloc((size_t)NP * Hh * 2);
  _Float16* Bhi = (_Float16*)alloc((size_t)8 * 24 * 4 * 16 * 8 * 2);
  _Float16* Blo = (_Float16*)alloc((size_t)8 * 24 * 4 * 16 * 8 * 2);
  _Float16* Bmh = (_Float16*)alloc((size_t)1024 * 8 * 2);
  _Float16* Bml = (_Float16*)alloc((size_t)1024 * 8 * 2);
  float* dis = (float*)alloc((size_t)Nn * 4);
  unsigned long long* pk = (unsigned long long*)alloc((size_t)Nn * 8);
  int* rowptr = (int*)alloc((size_t)(Nn + 1) * 4);
  int* cursor = (int*)alloc((size_t)Nn * 4);
  int* bsum = (int*)alloc(512 * 4);
  int* bpre = (int*)alloc(512 * 4);
  int* csr_src = (int*)alloc((size_t)Ee * 4);
  float* csr_w = (float*)alloc((size_t)Ee * 4);
  (void)ws_size;
  (void)in_sizes;
  (void)n_in;
  (void)out_size;

  const int NB = (Nn + 255) / 256;  // 391
  const int EB = (Ee + 255) / 256;  // 2344

  hipMemsetAsync(pk, 0, (size_t)Nn * 8, stream);
  count_kernel<<<EB, 256, 0, stream>>>(ei, pk);
  scan_partial<<<NB, 256, 0, stream>>>(pk, dis, bsum);
  scan_bsums<<<1, 512, 0, stream>>>(bsum, bpre, NB);
  scan_final<<<NB, 256, 0, stream>>>(pk, bpre, rowptr, cursor);
  fill_kernel<<<EB, 256, 0, stream>>>(ei, dis, cursor, csr_src, csr_w);
  prep_misc<<<52 + (NP * 16) / 256, 256, 0, stream>>>(Wih, Whh, Bhi, Blo, Wm1, Bmh,
                                                      Bml, X, W0, b0, Hs[0]);

  for (int t = 1; t <= 4; ++t) {
    gcn_gru_fused<<<NT, 512, 0, stream>>>(Hs[t - 1], Hs[t], csr_src, csr_w,
                                          rowptr, Bhi, Blo, bih, bhh);
  }
  gcn_gru_last2<<<NT, 512, 0, stream>>>(Hs[4], Hs[1], Hs[2], Hs[3], csr_src, csr_w,
                                        rowptr, Bhi, Blo, bih, bhh, Bmh, Bml,
                                        bm1, Wm2, bm2, out);
}